// Round 8
// baseline (301.849 us; speedup 1.0000x reference)
//
#include <hip/hip_runtime.h>
#include <hip/hip_bf16.h>

#define AS1 __attribute__((address_space(1)))
#define AS3 __attribute__((address_space(3)))

typedef __bf16 bf16x8_t __attribute__((ext_vector_type(8)));
typedef float f32x4_t __attribute__((ext_vector_type(4)));
typedef unsigned short ushort_t;
typedef unsigned int uint_t;

static __device__ __forceinline__ ushort_t f2b(float f) {
    __hip_bfloat16 h = __float2bfloat16(f);
    return __builtin_bit_cast(unsigned short, h);
}
static __device__ __forceinline__ float b2f(ushort_t u) {
    return __uint_as_float((uint_t)u << 16);
}

// ---------------------------------------------------------------- fused casts (one launch)
struct CastArgs {
    const float* src[5];
    ushort_t* dst[5];
    int cum[6];   // prefix sums of float4-group counts
};

__global__ __launch_bounds__(256) void cast_all(CastArgs a) {
    const int i = blockIdx.x * 256 + threadIdx.x;
    if (i >= a.cum[5]) return;
    int s = 0;
#pragma unroll
    for (int k = 1; k < 5; ++k) s += (i >= a.cum[k]);
    const int idx = i - a.cum[s];
    float4 v = ((const float4*)a.src[s])[idx];
    ushort4 o;
    o.x = f2b(v.x); o.y = f2b(v.y); o.z = f2b(v.z); o.w = f2b(v.w);
    ((ushort4*)a.dst[s])[idx] = o;
}

// ---------------------------------------------------------------- bf16 MFMA GEMM, BK=64 (R5 core)
// C(MxN) = A(MxK) @ B^T (B stored NxK row-major), epilogue per FLAGS.
// 16x16x32 MFMA core (R6's 32x32x16 regressed: 4-way LDS conflicts).
// BK=64, XOR-swizzled LDS (chunk c at row r holds global chunk c^(r&7)):
// global_load_lds dests wave-uniform-contiguous, frag reads conflict-free
// (measured 0). Split-K over z (bf16 partial to pb.p[z] when EPI_PART).
#define EPI_BIAS 1
#define EPI_RELU 2
#define EPI_PART 8
#define EPI_OUTB 16

struct PB { ushort_t* p[4]; };

template <int F>
__global__ __launch_bounds__(256, 2) void gemm_bt(const ushort_t* __restrict__ A,
                                                  const ushort_t* __restrict__ B,
                                                  const float* __restrict__ bias,
                                                  PB pb,
                                                  ushort_t* __restrict__ outb,
                                                  int M, int N, int Kc, int ld) {
    __shared__ ushort_t la[128 * 64];
    __shared__ ushort_t lb[128 * 64];
    const int t = threadIdx.x;

    // XCD-aware swizzle (8 XCDs, round-robin dispatch: xcd = lid&7)
    const int nx = gridDim.x, ny = gridDim.y, nz = gridDim.z;
    const int lid = blockIdx.x + nx * (blockIdx.y + ny * blockIdx.z);
    const int xcd = lid & 7;
    const int slot = lid >> 3;
    int n_i, m_i, z;
    if (nx >= 16) {
        const int nhalf = nx >> 1, mq = ny >> 2;
        n_i = (xcd & 1) * nhalf + slot % nhalf;
        const int rest = slot / nhalf;
        z = rest % nz;
        m_i = (xcd >> 1) * mq + rest / nz;
    } else {
        n_i = slot % nx;
        const int rest = slot / nx;
        z = rest % nz;
        m_i = xcd * (ny >> 3) + rest / nz;
    }

    const int n0 = n_i * 128;
    const int m0 = m_i * 128;
    const int k0 = z * Kc;
    const int lane = t & 63;
    const int w = t >> 6;
    const int wr = w >> 1, wc = w & 1;
    const int r16 = lane & 15, kq = lane >> 4;

    f32x4_t acc[4][4] = {};

    size_t aoff[4], boff[4];
#pragma unroll
    for (int p = 0; p < 4; ++p) {
        const int c = t + 256 * p;
        const int row = c >> 3, cc = c & 7;
        const int gcol = (cc ^ (row & 7)) * 8;
        aoff[p] = (size_t)(m0 + row) * ld + gcol + k0;
        boff[p] = (size_t)(n0 + row) * ld + gcol + k0;
    }

    for (int kk = 0; kk < Kc; kk += 64) {
#pragma unroll
        for (int p = 0; p < 4; ++p) {
            __builtin_amdgcn_global_load_lds((AS1 void*)(A + aoff[p] + kk),
                                             (AS3 void*)(la + (t + 256 * p) * 8), 16, 0, 0);
            __builtin_amdgcn_global_load_lds((AS1 void*)(B + boff[p] + kk),
                                             (AS3 void*)(lb + (t + 256 * p) * 8), 16, 0, 0);
        }
        __syncthreads();
#pragma unroll
        for (int half = 0; half < 2; ++half) {
            const int sw = ((half * 4 + kq) ^ (r16 & 7)) * 8;
            bf16x8_t af[4], bfr[4];
#pragma unroll
            for (int mi = 0; mi < 4; ++mi)
                af[mi] = *(const bf16x8_t*)(la + (wr * 64 + mi * 16 + r16) * 64 + sw);
#pragma unroll
            for (int ni = 0; ni < 4; ++ni)
                bfr[ni] = *(const bf16x8_t*)(lb + (wc * 64 + ni * 16 + r16) * 64 + sw);
#pragma unroll
            for (int mi = 0; mi < 4; ++mi)
#pragma unroll
                for (int ni = 0; ni < 4; ++ni)
                    acc[mi][ni] = __builtin_amdgcn_mfma_f32_16x16x32_bf16(af[mi], bfr[ni], acc[mi][ni], 0, 0, 0);
        }
        __syncthreads();
    }

    ushort_t* po = (F & EPI_PART) ? pb.p[z] : outb;
#pragma unroll
    for (int mi = 0; mi < 4; ++mi) {
#pragma unroll
        for (int ni = 0; ni < 4; ++ni) {
            const int row = m0 + wr * 64 + mi * 16 + kq * 4;
            const int col = n0 + wc * 64 + ni * 16 + r16;
            float bv = (F & EPI_BIAS) ? bias[col] : 0.f;
#pragma unroll
            for (int i = 0; i < 4; ++i) {
                float v = acc[mi][ni][i] + bv;
                const size_t off = (size_t)(row + i) * N + col;
                if (F & EPI_RELU) v = fmaxf(v, 0.f);
                po[off] = f2b(v);
            }
        }
    }
}

// ---------------------------------------------------------------- MFMA banded flash attention
// qkv: (B*S, 3072) bf16 rows [q | k | v], head h owns cols h*64..h*64+63 of each third.
// Fixed-max softmax: scores |s| <~ 10 << 88, so exp() without running max is
// numerically safe -> no alpha rescale, no row-max reduction.
// V layout: stride-64 XOR-swizzled (oct' = oct ^ ((key + 2*(key>>3)) & 7)):
// staging writes full uint4 conflict-free; scalar frag gathers spread across
// all 32 banks (2 lanes/dword broadcast = free) vs 4-way on padded stride.
__global__ __launch_bounds__(256, 4) void flash_mfma(const ushort_t* __restrict__ qkv,
                                                     ushort_t* __restrict__ attn) {
    const int S = 2048;
    const int h = blockIdx.y, bb = blockIdx.z;
    const int q0 = blockIdx.x * 64;
    const int t = threadIdx.x;
    const int w = t >> 6, lane = t & 63;
    const int r16 = lane & 15, g = lane >> 4;

    __shared__ ushort_t lk[64 * 72];
    __shared__ ushort_t lv[64 * 64];
    __shared__ ushort_t lp[4 * 16 * 72];

    const ushort_t* base = qkv + (size_t)bb * S * 3072 + (size_t)h * 64;

    bf16x8_t qa[2];
    {
        const ushort_t* qrow = base + (size_t)(q0 + 16 * w + r16) * 3072;
        qa[0] = *(const bf16x8_t*)(qrow + g * 8);
        qa[1] = *(const bf16x8_t*)(qrow + 32 + g * 8);
    }

    f32x4_t O[4] = {};
    float lrow[4] = {0.f, 0.f, 0.f, 0.f};

    for (int it = 0; it < 5; ++it) {
        const int kt0 = q0 - 128 + 64 * it;
        if (kt0 < 0 || kt0 >= S) continue;

#pragma unroll
        for (int pass = 0; pass < 2; ++pass) {
            const int c = t + 256 * pass;
            const int key = c >> 3, dc = c & 7;
            const ushort_t* src = base + (size_t)(kt0 + key) * 3072 + dc * 8;
            uint4 kk = *(const uint4*)(src + 1024);
            uint4 vv = *(const uint4*)(src + 2048);
            *(uint4*)(lk + key * 72 + dc * 8) = kk;
            const int vo = (dc ^ ((key + 2 * (key >> 3)) & 7)) * 8;
            *(uint4*)(lv + key * 64 + vo) = vv;
        }
        __syncthreads();

        // QK^T: 16q x 64k, C layout
        f32x4_t s[4];
#pragma unroll
        for (int sub = 0; sub < 4; ++sub) {
            const ushort_t* krow = lk + (16 * sub + r16) * 72;
            bf16x8_t kb0 = *(const bf16x8_t*)(krow + g * 8);
            bf16x8_t kb1 = *(const bf16x8_t*)(krow + 32 + g * 8);
            f32x4_t z = {};
            z = __builtin_amdgcn_mfma_f32_16x16x32_bf16(qa[0], kb0, z, 0, 0, 0);
            z = __builtin_amdgcn_mfma_f32_16x16x32_bf16(qa[1], kb1, z, 0, 0, 0);
            s[sub] = z;
        }

        // fixed-max softmax: p = band ? exp(s/8) : 0; l += sum(p)
        ushort_t* pw = lp + w * 16 * 72;
#pragma unroll
        for (int reg = 0; reg < 4; ++reg) {
            const int i = q0 + 16 * w + g * 4 + reg;
            float rs = 0.f;
#pragma unroll
            for (int sub = 0; sub < 4; ++sub) {
                const int j = kt0 + 16 * sub + r16;
                const int d = i - j;
                const bool valid = (d <= 128) && (d >= -128);
                float p = valid ? __expf(s[sub][reg] * 0.125f) : 0.f;
                pw[(g * 4 + reg) * 72 + 16 * sub + r16] = f2b(p);
                rs += p;
            }
#pragma unroll
            for (int msk = 1; msk < 16; msk <<= 1) rs += __shfl_xor(rs, msk);
            lrow[reg] += rs;
        }

        // PV: O += P @ V
        bf16x8_t pa0 = *(const bf16x8_t*)(pw + r16 * 72 + g * 8);
        bf16x8_t pa1 = *(const bf16x8_t*)(pw + r16 * 72 + 32 + g * 8);
        const __bf16* lvb = (const __bf16*)lv;
#pragma unroll
        for (int dd = 0; dd < 4; ++dd) {
            const int oct = dd * 2 + (r16 >> 3), off = r16 & 7;
            bf16x8_t vb0, vb1;
#pragma unroll
            for (int j = 0; j < 8; ++j) {
                const int ka = g * 8 + j, kb = 32 + g * 8 + j;
                vb0[j] = lvb[ka * 64 + ((oct ^ ((ka + 2 * (ka >> 3)) & 7)) << 3) + off];
                vb1[j] = lvb[kb * 64 + ((oct ^ ((kb + 2 * (kb >> 3)) & 7)) << 3) + off];
            }
            O[dd] = __builtin_amdgcn_mfma_f32_16x16x32_bf16(pa0, vb0, O[dd], 0, 0, 0);
            O[dd] = __builtin_amdgcn_mfma_f32_16x16x32_bf16(pa1, vb1, O[dd], 0, 0, 0);
        }
        __syncthreads();
    }

#pragma unroll
    for (int reg = 0; reg < 4; ++reg) {
        const float inv = 1.0f / lrow[reg];
        const int i = q0 + 16 * w + g * 4 + reg;
        ushort_t* orow = attn + ((size_t)(bb * S + i)) * 1024 + (size_t)h * 64;
#pragma unroll
        for (int dd = 0; dd < 4; ++dd)
            orow[dd * 16 + r16] = f2b(O[dd][reg] * inv);
    }
}

// ---------------------------------------------------------------- LayerNorm + split-K reduce
// v = sum(bf16 partials) + bias + bf16 residual -> LN -> outf (f32, opt) / outb (bf16, opt)
template <int NP>
__global__ __launch_bounds__(256) void ln_red(const ushort_t* __restrict__ p0,
                                              const ushort_t* __restrict__ p1,
                                              const ushort_t* __restrict__ p2,
                                              const ushort_t* __restrict__ p3,
                                              const float* __restrict__ bias,
                                              const ushort_t* __restrict__ resb,
                                              const float* __restrict__ g,
                                              const float* __restrict__ bta,
                                              float* __restrict__ outf,
                                              ushort_t* __restrict__ outb) {
    const int row = blockIdx.x;
    const int t = threadIdx.x;
    const size_t idx = (size_t)row * 256 + t;
    float4 v;
    {
        ushort4 a = ((const ushort4*)p0)[idx];
        ushort4 b = ((const ushort4*)p1)[idx];
        v.x = b2f(a.x) + b2f(b.x);
        v.y = b2f(a.y) + b2f(b.y);
        v.z = b2f(a.z) + b2f(b.z);
        v.w = b2f(a.w) + b2f(b.w);
    }
    if (NP == 4) {
        ushort4 a = ((const ushort4*)p2)[idx];
        ushort4 b = ((const ushort4*)p3)[idx];
        v.x += b2f(a.x) + b2f(b.x);
        v.y += b2f(a.y) + b2f(b.y);
        v.z += b2f(a.z) + b2f(b.z);
        v.w += b2f(a.w) + b2f(b.w);
    }
    {
        float4 bb = ((const float4*)bias)[t];
        ushort4 rr = ((const ushort4*)resb)[idx];
        v.x += bb.x + b2f(rr.x); v.y += bb.y + b2f(rr.y);
        v.z += bb.z + b2f(rr.z); v.w += bb.w + b2f(rr.w);
    }

    float s = v.x + v.y + v.z + v.w;
    float s2 = v.x * v.x + v.y * v.y + v.z * v.z + v.w * v.w;
#pragma unroll
    for (int off = 32; off > 0; off >>= 1) {
        s += __shfl_down(s, off);
        s2 += __shfl_down(s2, off);
    }
    __shared__ float red[8];
    const int w = t >> 6, lane = t & 63;
    if (lane == 0) { red[w] = s; red[4 + w] = s2; }
    __syncthreads();
    float S1 = red[0] + red[1] + red[2] + red[3];
    float S2 = red[4] + red[5] + red[6] + red[7];
    float mean = S1 * (1.f / 1024.f);
    float var = S2 * (1.f / 1024.f) - mean * mean;
    float r = rsqrtf(var + 1e-5f);
    float4 gg = ((const float4*)g)[t];
    float4 bb = ((const float4*)bta)[t];
    float4 o;
    o.x = (v.x - mean) * r * gg.x + bb.x;
    o.y = (v.y - mean) * r * gg.y + bb.y;
    o.z = (v.z - mean) * r * gg.z + bb.z;
    o.w = (v.w - mean) * r * gg.w + bb.w;
    if (outf) ((float4*)outf)[idx] = o;
    if (outb) {
        ushort4 ob;
        ob.x = f2b(o.x); ob.y = f2b(o.y); ob.z = f2b(o.z); ob.w = f2b(o.w);
        ((ushort4*)outb)[idx] = ob;
    }
}

// ---------------------------------------------------------------- launch
extern "C" void kernel_launch(void* const* d_in, const int* in_sizes, int n_in,
                              void* d_out, int out_size, void* d_ws, size_t ws_size,
                              hipStream_t stream) {
    const float* x          = (const float*)d_in[0];
    const float* in_proj_w  = (const float*)d_in[1];
    const float* in_proj_b  = (const float*)d_in[2];
    const float* out_proj_w = (const float*)d_in[3];
    const float* out_proj_b = (const float*)d_in[4];
    const float* ln1_g      = (const float*)d_in[5];
    const float* ln1_b      = (const float*)d_in[6];
    const float* w1         = (const float*)d_in[7];
    const float* b1         = (const float*)d_in[8];
    const float* w2         = (const float*)d_in[9];
    const float* b2         = (const float*)d_in[10];
    const float* ln2_g      = (const float*)d_in[11];
    const float* ln2_b      = (const float*)d_in[12];

    char* ws = (char*)d_ws;
    ushort_t* xb    = (ushort_t*)(ws + (0ull << 20));    //  8 MB: x bf16       (4096x1024)
    ushort_t* wqkvb = (ushort_t*)(ws + (8ull << 20));    //  6 MB: in_proj_w    (3072x1024)
    ushort_t* woutb = (ushort_t*)(ws + (14ull << 20));   //  2 MB: out_proj_w   (1024x1024)
    ushort_t* w1b   = (ushort_t*)(ws + (16ull << 20));   //  8 MB: w1           (4096x1024)
    ushort_t* w2b   = (ushort_t*)(ws + (24ull << 20));   //  8 MB: w2           (1024x4096)
    ushort_t* qkvb  = (ushort_t*)(ws + (32ull << 20));   // 24 MB: qkv bf16     (4096x3072)
    ushort_t* attnb = (ushort_t*)(ws + (56ull << 20));   //  8 MB: attn bf16    (4096x1024)
    ushort_t* x2b   = (ushort_t*)(ws + (96ull << 20));   //  8 MB: x2 bf16
    ushort_t* hb    = (ushort_t*)(ws + (104ull << 20));  // 32 MB: relu hidden  (4096x4096)
    // bf16 split-K partials (8 MB each) in regions dead at their phase:
    ushort_t* op_p0 = (ushort_t*)(ws + (64ull << 20));   // out_proj p0
    ushort_t* op_p1 = (ushort_t*)(ws + (72ull << 20));   // out_proj p1
    ushort_t* op_p2 = (ushort_t*)(ws + (32ull << 20));   // out_proj p2 (qkvb dead after flash)
    ushort_t* op_p3 = (ushort_t*)(ws + (40ull << 20));   // out_proj p3 (qkvb dead after flash)
    ushort_t* f2_p0 = (ushort_t*)(ws + (80ull << 20));   // FFN2 p0
    ushort_t* f2_p1 = (ushort_t*)(ws + (8ull << 20));    // FFN2 p1 (wqkvb dead)
    ushort_t* f2_p2 = (ushort_t*)(ws + (32ull << 20));   // FFN2 p2 (qkvb dead)
    ushort_t* f2_p3 = (ushort_t*)(ws + (40ull << 20));   // FFN2 p3 (qkvb dead)
    (void)in_sizes; (void)n_in; (void)out_size; (void)ws_size;

    // ---- one fused cast launch
    CastArgs ca;
    ca.src[0] = x;  ca.dst[0] = xb;
    ca.src[1] = in_proj_w;  ca.dst[1] = wqkvb;
    ca.src[2] = out_proj_w; ca.dst[2] = woutb;
    ca.src[3] = w1; ca.dst[3] = w1b;
    ca.src[4] = w2; ca.dst[4] = w2b;
    ca.cum[0] = 0;
    ca.cum[1] = 1048576;
    ca.cum[2] = 1048576 + 786432;
    ca.cum[3] = 1048576 + 786432 + 262144;
    ca.cum[4] = 1048576 + 786432 + 262144 + 1048576;
    ca.cum[5] = 1048576 + 786432 + 262144 + 1048576 + 1048576;
    cast_all<<<(ca.cum[5] + 255) / 256, 256, 0, stream>>>(ca);

    PB none = {{nullptr, nullptr, nullptr, nullptr}};

    // qkv = x @ in_proj_w.T + b   -> bf16
    gemm_bt<EPI_BIAS | EPI_OUTB><<<dim3(24, 32, 1), 256, 0, stream>>>(
        xb, wqkvb, in_proj_b, none, qkvb, 4096, 3072, 1024, 1024);

    // banded MFMA flash attention -> attnb bf16
    flash_mfma<<<dim3(32, 16, 2), 256, 0, stream>>>(qkvb, attnb);

    // out_proj split-K x4 -> bf16 partials (4 blocks/CU)
    PB op = {{op_p0, op_p1, op_p2, op_p3}};
    gemm_bt<EPI_PART><<<dim3(8, 32, 4), 256, 0, stream>>>(
        attnb, woutb, nullptr, op, nullptr, 4096, 1024, 256, 1024);

    // x2 = LN1(p0..p3 + out_proj_b + x[bf16]) -> bf16
    ln_red<4><<<4096, 256, 0, stream>>>(op_p0, op_p1, op_p2, op_p3,
                                        out_proj_b, xb, ln1_g, ln1_b, nullptr, x2b);

    // h = relu(x2 @ w1.T + b1) -> bf16
    gemm_bt<EPI_BIAS | EPI_RELU | EPI_OUTB><<<dim3(32, 32, 1), 256, 0, stream>>>(
        x2b, w1b, b1, none, hb, 4096, 4096, 1024, 1024);

    // FFN2 split-K x4 -> bf16 partials
    PB f2 = {{f2_p0, f2_p1, f2_p2, f2_p3}};
    gemm_bt<EPI_PART><<<dim3(8, 32, 4), 256, 0, stream>>>(
        hb, w2b, nullptr, f2, nullptr, 4096, 1024, 1024, 4096);

    // out = LN2(p0+p1+p2+p3 + b2 + x2[bf16]) -> f32 d_out
    ln_red<4><<<4096, 256, 0, stream>>>(f2_p0, f2_p1, f2_p2, f2_p3,
                                        b2, x2b, ln2_g, ln2_b, (float*)d_out, nullptr);
}